// Round 7
// baseline (290.609 us; speedup 1.0000x reference)
//
#include <hip/hip_runtime.h>
#include <hip/hip_bf16.h>

// ---------------- problem constants ----------------
constexpr int Bn = 8, Cn = 128, Hn = 64, Wn = 64, HWn = Hn * Wn;
constexpr int DGn = 8, Kn = 9, CMn = 216;          // CM = DG*3*K
constexpr int Hs = 32, Ws = 32, HWs = Hs * Ws;

typedef __attribute__((ext_vector_type(8))) short bf16x8;
typedef __attribute__((ext_vector_type(4))) float f32x4;

// ---------------- workspace layout (float offsets) ----------------
constexpr long OFF_FLAG = 0;                        // int flag at word 0
constexpr long OFF_FL   = 256;                      // feat_l f32   [8][128][4096]
constexpr long OFF_FS   = OFF_FL  + (long)Bn*Cn*HWn;      // feat_s f32 [8][128][1024]
constexpr long OFF_W1T  = OFF_FS  + (long)Bn*Cn*HWs;      // w1t [b][c][o] 8*128*128
constexpr long OFF_WOT  = OFF_W1T + (long)Bn*Cn*Cn;       // w_offT [c 256][o 128] (2x folded)
constexpr long OFF_WCT  = OFF_WOT + (long)2*Cn*Cn;        // w_cm bf16 slices [18][224][128B-swz]
constexpr long OFF_WDT  = OFF_WCT + (long)Cn*Kn*224;      // w_dcn bf16 [k][o][c]
constexpr long OFF_BCM  = OFF_WDT + (long)Kn*Cn*Cn;       // b_cm (216, padded 256)
constexpr long OFF_BDC  = OFF_BCM + 256;                  // b_dcn (128, padded 256)
constexpr long OFF_GAP  = OFF_BDC + 256;                  // gap [b][c]
constexpr long OFF_AT   = OFF_GAP + (long)Bn*Cn;          // 1+sigmoid(atten) [b][c]
constexpr long OFF_FUP  = OFF_AT  + (long)Bn*Cn;          // feat_up f32 [8][128][4096]
constexpr long OFF_ARM  = OFF_FUP + (long)Bn*Cn*HWn;      // feat_arm f32
constexpr long OFF_OFT  = OFF_ARM + (long)Bn*Cn*HWn;      // off_feat bf16 NHWC [8][4096][128]
constexpr long OFF_OM   = OFF_OFT + (long)Bn*Cn*HWn;      // om f32 [b][h][216][64]
constexpr long OFF_FUPB = OFF_OM  + (long)Bn*CMn*HWn;     // fup bf16 NHWC [8][4096][128]

static __device__ __forceinline__ float ldin(const void* p, long i, bool isbf) {
  if (isbf) return __bfloat162float(((const __hip_bfloat16*)p)[i]);
  return ((const float*)p)[i];
}

// f32 -> bf16 bits (RNE, finite inputs)
static __device__ __forceinline__ unsigned short f2b(float f) {
  unsigned u = __builtin_bit_cast(unsigned, f);
  u += 0x7FFFu + ((u >> 16) & 1u);
  return (unsigned short)(u >> 16);
}
static __device__ __forceinline__ unsigned pack2(float v0, float v1) {
  return ((unsigned)f2b(v1) << 16) | (unsigned)f2b(v0);
}
static __device__ __forceinline__ float b2f(unsigned short s) {
  return __builtin_bit_cast(float, ((unsigned)s) << 16);
}

#define GLOAD_LDS16(g, l) __builtin_amdgcn_global_load_lds( \
    (const __attribute__((address_space(1))) void*)(g),     \
    (__attribute__((address_space(3))) void*)(l), 16, 0, 0)

// ---------------- dtype detector ----------------
__global__ __launch_bounds__(256) void k_detect(const unsigned int* __restrict__ p,
                                                int* __restrict__ flag) {
  __shared__ int cnt[256];
  int t = threadIdx.x;
  int c = 0;
  for (int i = 0; i < 4; ++i) {
    unsigned v = p[t * 4 + i];
    unsigned e = (v >> 7) & 0xFFu;
    c += (e >= 118u && e <= 130u) ? 1 : 0;
  }
  cnt[t] = c;
  __syncthreads();
  for (int s = 128; s > 0; s >>= 1) {
    if (t < s) cnt[t] += cnt[t + s];
    __syncthreads();
  }
  if (t == 0) *flag = (cnt[0] > 512) ? 1 : 0;
}

// ---------------- input conversion ----------------
__global__ __launch_bounds__(256) void k_cvt(const void* __restrict__ src,
                                             float* __restrict__ dst, int n,
                                             const int* __restrict__ flag) {
  int stride = gridDim.x * blockDim.x;
  int i0 = blockIdx.x * blockDim.x + threadIdx.x;
  if (*flag) {
    const __hip_bfloat16* s = (const __hip_bfloat16*)src;
    for (int i = i0; i < n; i += stride) dst[i] = __bfloat162float(s[i]);
  } else {
    const float* s = (const float*)src;
    for (int i = i0; i < n; i += stride) dst[i] = s[i];
  }
}

// w_off [o 128][c 256] -> [c 256][o 128], with 2.0x folded for c>=128
__global__ __launch_bounds__(256) void k_woffT(const void* __restrict__ src,
                                               float* __restrict__ dst,
                                               const int* __restrict__ flag) {
  int i = blockIdx.x * 256 + threadIdx.x;
  if (i >= 2 * Cn * Cn) return;
  int c = i >> 7, o = i & 127;
  bool isbf = (*flag != 0);
  float v = ldin(src, (long)o * 256 + c, isbf);
  if (c >= Cn) v *= 2.0f;
  dst[i] = v;
}

// w_cm [oc 216][c 128][k 9] -> bf16 slices [s 18][oc 224][chunk-swizzled 128B]
__global__ __launch_bounds__(256) void k_wcmB(const void* __restrict__ src,
                                              unsigned short* __restrict__ dst,
                                              const int* __restrict__ flag) {
  int i = blockIdx.x * 256 + threadIdx.x;
  if (i >= 18 * 224 * 64) return;
  int s = i / (224 * 64);
  int rem = i % (224 * 64);
  int oc = rem >> 6;
  int c_off = rem & 63;
  int tap = s >> 1, ck = s & 1;
  int c = ck * 64 + c_off;
  bool isbf = (*flag != 0);
  float v = 0.f;
  if (oc < CMn) v = ldin(src, ((long)oc * Cn + c) * Kn + tap, isbf);
  int chunk = c_off >> 3, e = c_off & 7;
  int pc = chunk ^ (oc & 7);
  dst[(long)s * 14336 + oc * 64 + pc * 8 + e] = f2b(v);
}

// w_dcn [o 128][c 128][k 9] -> bf16 [k][o][c]
__global__ __launch_bounds__(256) void k_wdcnB(const void* __restrict__ src,
                                               unsigned short* __restrict__ dst,
                                               const int* __restrict__ flag) {
  int i = blockIdx.x * 256 + threadIdx.x;
  if (i >= Kn * Cn * Cn) return;
  int k = i / (Cn * Cn);
  int o = (i >> 7) & 127;
  int c = i & 127;
  bool isbf = (*flag != 0);
  float v = ldin(src, ((long)o * Cn + c) * Kn + k, isbf);
  dst[i] = f2b(v);
}

// ---------------- gap ----------------
__global__ __launch_bounds__(256) void k_gap(const float* __restrict__ fl,
                                             float* __restrict__ gap) {
  __shared__ float red[256];
  int bc = blockIdx.x, t = threadIdx.x;
  const float* p = fl + (long)bc * HWn;
  float s = 0.f;
  for (int i = t; i < HWn; i += 256) s += p[i];
  red[t] = s;
  __syncthreads();
  for (int k = 128; k > 0; k >>= 1) {
    if (t < k) red[t] += red[t + k];
    __syncthreads();
  }
  if (t == 0) gap[bc] = red[0] * (1.0f / HWn);
}

// ---------------- atten ----------------
__global__ __launch_bounds__(256) void k_atten(const float* __restrict__ gap,
                                               const void* __restrict__ wat,
                                               float* __restrict__ at1p,
                                               const int* __restrict__ flag) {
  int tid = blockIdx.x * 256 + threadIdx.x;
  if (tid >= Bn * Cn) return;
  int b = tid >> 7, o = tid & 127;
  bool isbf = (*flag != 0);
  const float* g = gap + b * Cn;
  float s = 0.f;
  for (int c = 0; c < Cn; ++c) s += g[c] * ldin(wat, (long)o * Cn + c, isbf);
  at1p[tid] = 1.0f + 1.0f / (1.0f + expf(-s));
}

// w1t[b][c][o] = w_fsm[o][c] * (1 + atten[b][c])
__global__ __launch_bounds__(256) void k_w1t(const void* __restrict__ wfsm,
                                             const float* __restrict__ at1p,
                                             float* __restrict__ dst,
                                             const int* __restrict__ flag) {
  int i = blockIdx.x * 256 + threadIdx.x;
  if (i >= Bn * Cn * Cn) return;
  int b = i >> 14, c = (i >> 7) & 127, o = i & 127;
  bool isbf = (*flag != 0);
  dst[i] = ldin(wfsm, (long)o * Cn + c, isbf) * at1p[b * Cn + c];
}

// ---------------- bilinear 2x upsample (f32 NCHW) ----------------
__global__ __launch_bounds__(256) void k_up(const float* __restrict__ fs,
                                            float* __restrict__ fup) {
  int idx = blockIdx.x * 256 + threadIdx.x;
  if (idx >= Bn * Cn * HWn) return;
  int w = idx & 63, h = (idx >> 6) & 63, bc = idx >> 12;
  const float* s = fs + (long)bc * HWs;
  int iy0; float fy;
  if (h & 1) { iy0 = (h - 1) >> 1; fy = 0.25f; } else { iy0 = (h >> 1) - 1; fy = 0.75f; }
  int ix0; float fx;
  if (w & 1) { ix0 = (w - 1) >> 1; fx = 0.25f; } else { ix0 = (w >> 1) - 1; fx = 0.75f; }
  int iy1 = min(iy0 + 1, Hs - 1); iy0 = max(iy0, 0);
  int ix1 = min(ix0 + 1, Ws - 1); ix0 = max(ix0, 0);
  float v = (1.f - fy) * ((1.f - fx) * s[iy0 * Ws + ix0] + fx * s[iy0 * Ws + ix1]) +
            fy        * ((1.f - fx) * s[iy1 * Ws + ix0] + fx * s[iy1 * Ws + ix1]);
  fup[idx] = v;
}

// ---------------- fup f32 NCHW -> bf16 NHWC transpose ----------------
__global__ __launch_bounds__(256) void k_upb(const float* __restrict__ fup,
                                             unsigned short* __restrict__ fupb) {
  __shared__ float xs[128][65];
  const int b = blockIdx.y, p0 = blockIdx.x * 64, t = threadIdx.x;
  const float* src = fup + (long)b * Cn * HWn + p0;
  for (int i = t; i < 128 * 64; i += 256) {
    int c = i >> 6, p = i & 63;
    xs[c][p] = src[(long)c * HWn + p];
  }
  __syncthreads();
  for (int i = t; i < 1024; i += 256) {
    int p = i >> 4, ch = (i & 15) * 8;
    uint4 pk;
    pk.x = pack2(xs[ch + 0][p], xs[ch + 1][p]);
    pk.y = pack2(xs[ch + 2][p], xs[ch + 3][p]);
    pk.z = pack2(xs[ch + 4][p], xs[ch + 5][p]);
    pk.w = pack2(xs[ch + 6][p], xs[ch + 7][p]);
    *(uint4*)(fupb + (((long)(b * HWn + p0 + p)) << 7) + ch) = pk;
  }
}

// ---------------- feat_arm ----------------
__global__ __launch_bounds__(256) void k_farm(const float* __restrict__ fl,
                                              const float* __restrict__ w1t,
                                              float* __restrict__ farm) {
  const int t = threadIdx.x;
  const int b = blockIdx.z, og = blockIdx.y;
  const int pos = blockIdx.x * 256 + t;
  const float* x = fl + (long)b * Cn * HWn + pos;
  const float* wb = w1t + (long)b * Cn * Cn + og * 8;
  float acc[8];
#pragma unroll
  for (int o = 0; o < 8; ++o) acc[o] = 0.f;
  for (int c = 0; c < Cn; ++c) {
    float xv = x[(long)c * HWn];
    const float4* w4 = (const float4*)(wb + (long)c * Cn);
    float4 wa = w4[0], wc = w4[1];
    acc[0] += xv * wa.x; acc[1] += xv * wa.y; acc[2] += xv * wa.z; acc[3] += xv * wa.w;
    acc[4] += xv * wc.x; acc[5] += xv * wc.y; acc[6] += xv * wc.z; acc[7] += xv * wc.w;
  }
#pragma unroll
  for (int o = 0; o < 8; ++o)
    farm[(long)(b * Cn + og * 8 + o) * HWn + pos] = acc[o];
}

// ---------------- off_feat -> bf16 NHWC [b][pos][c] ----------------
__global__ __launch_bounds__(256) void k_offf(const float* __restrict__ arm,
                                              const float* __restrict__ fup,
                                              const float* __restrict__ wot,
                                              unsigned short* __restrict__ oftb) {
  const int t = threadIdx.x;
  const int b = blockIdx.z, og = blockIdx.y;
  const int pos = blockIdx.x * 256 + t;
  const float* xa = arm + (long)b * Cn * HWn + pos;
  const float* xu = fup + (long)b * Cn * HWn + pos;
  const float* wg = wot + og * 8;
  float acc[8];
#pragma unroll
  for (int o = 0; o < 8; ++o) acc[o] = 0.f;
  for (int c = 0; c < Cn; ++c) {
    float xv = xa[(long)c * HWn];
    const float4* w4 = (const float4*)(wg + (long)c * Cn);
    float4 wa = w4[0], wc = w4[1];
    acc[0] += xv * wa.x; acc[1] += xv * wa.y; acc[2] += xv * wa.z; acc[3] += xv * wa.w;
    acc[4] += xv * wc.x; acc[5] += xv * wc.y; acc[6] += xv * wc.z; acc[7] += xv * wc.w;
  }
  for (int c = 0; c < Cn; ++c) {
    float xv = xu[(long)c * HWn];
    const float4* w4 = (const float4*)(wg + (long)(Cn + c) * Cn);
    float4 wa = w4[0], wc = w4[1];
    acc[0] += xv * wa.x; acc[1] += xv * wa.y; acc[2] += xv * wa.z; acc[3] += xv * wa.w;
    acc[4] += xv * wc.x; acc[5] += xv * wc.y; acc[6] += xv * wc.z; acc[7] += xv * wc.w;
  }
  uint4 pk;
  pk.x = pack2(acc[0], acc[1]); pk.y = pack2(acc[2], acc[3]);
  pk.z = pack2(acc[4], acc[5]); pk.w = pack2(acc[6], acc[7]);
  *(uint4*)(oftb + (((long)b * HWn + pos) << 7) + og * 8) = pk;
}

// ---------------- 3x3 conv via bf16 MFMA, LDS-staged weights -> om ----------------
// om output layout: [b][h][216][64] (w-contiguous rows for k_dcn coalescing).
__global__ __launch_bounds__(256) void k_convcm(const unsigned short* __restrict__ xb,
                                                const unsigned short* __restrict__ wsl,
                                                const float* __restrict__ bcm,
                                                float* __restrict__ om) {
  __shared__ unsigned short wlds[2][14336];   // 2 x 28,672 B
  const int h = blockIdx.x, b = blockIdx.y;
  const int t = threadIdx.x, lane = t & 63, wv = t >> 6;
  const int mi = wv & 1, ni = wv >> 1;
  const int lm = lane & 15, lh = lane >> 4;

  f32x4 acc[2][7];
#pragma unroll
  for (int mt = 0; mt < 2; ++mt)
#pragma unroll
    for (int nt = 0; nt < 7; ++nt) acc[mt][nt] = (f32x4){0.f, 0.f, 0.f, 0.f};

  auto stage = [&](int s, int bufi) {
    const char* src = (const char*)(wsl + (long)s * 14336);
    char* dstb = (char*)&wlds[bufi][0];
#pragma unroll
    for (int i2 = 0; i2 < 7; ++i2) {
      int off = (wv * 7 + i2) * 1024;
      GLOAD_LDS16(src + off + lane * 16, dstb + off);
    }
  };

  stage(0, 0);
  __syncthreads();

  for (int s = 0; s < 18; ++s) {
    const int cur = s & 1;
    if (s < 17) stage(s + 1, cur ^ 1);
    const int tap = s >> 1, ck = s & 1;
    const int ky = tap / 3, kx = tap % 3;
    const int gy = h + ky - 1;
    const bool gyok = ((unsigned)gy < (unsigned)Hn);
    const int gyc = min(max(gy, 0), Hn - 1);

    bf16x8 af[2][2];
#pragma unroll
    for (int mt = 0; mt < 2; ++mt) {
      int wpos = mi * 32 + mt * 16 + lm;
      int gx = wpos + kx - 1;
      bool ok = gyok && ((unsigned)gx < (unsigned)Wn);
      int gxc = min(max(gx, 0), Wn - 1);
      const unsigned short* ap = xb + (((long)(b * HWn + gyc * Wn + gxc)) << 7)
                                    + ck * 64 + lh * 8;
#pragma unroll
      for (int ksub = 0; ksub < 2; ++ksub) {
        bf16x8 v = *(const bf16x8*)(ap + ksub * 32);
        af[mt][ksub] = ok ? v : (bf16x8)(short)0;
      }
    }

    const char* wbase = (const char*)&wlds[cur][0];
#pragma unroll
    for (int ksub = 0; ksub < 2; ++ksub) {
      int jj = ksub * 4 + lh;
#pragma unroll
      for (int nt = 0; nt < 7; ++nt) {
        int oc = ni * 112 + nt * 16 + lm;
        bf16x8 bfv = *(const bf16x8*)(wbase + oc * 128 + ((jj ^ (oc & 7)) << 4));
#pragma unroll
        for (int mt = 0; mt < 2; ++mt)
          acc[mt][nt] = __builtin_amdgcn_mfma_f32_16x16x32_bf16(
              af[mt][ksub], bfv, acc[mt][nt], 0, 0, 0);
      }
    }
    __syncthreads();
  }

#pragma unroll
  for (int nt = 0; nt < 7; ++nt) {
    int ch = ni * 112 + nt * 16 + lm;
    if (ch >= CMn) continue;
    float bias = bcm[ch];
#pragma unroll
    for (int mt = 0; mt < 2; ++mt) {
#pragma unroll
      for (int r = 0; r < 4; ++r) {
        int w = mi * 32 + mt * 16 + lh * 4 + r;
        float v = acc[mt][nt][r] + bias;
        if (ch >= 144) v = 1.0f / (1.0f + expf(-v));
        om[((long)((b * Hn + h) * CMn + ch) << 6) + w] = v;
      }
    }
  }
}

// ---------------- fused DCN v2: barrier-free, 1 wave = M16 x N128 ----------------
// Lane (lm = lane&15, cq = lane>>4): w = w0+lm, channels [cq*32, cq*32+32)
// spanning deform groups g0=2cq (first 16 ch) and g1=2cq+1 (second 16 ch).
// Wave-private LDS val tile: 16 rows x 264B (2-way banks max), double-buffered
// by tap parity. No __syncthreads anywhere: ds_write -> ds_read is same-wave.
__global__ __launch_bounds__(64, 3) void k_dcn(const float* __restrict__ om,
                                               const unsigned short* __restrict__ fupb,
                                               const unsigned short* __restrict__ wdb,
                                               const float* __restrict__ bdc,
                                               const float* __restrict__ farm,
                                               void* __restrict__ out,
                                               const int* __restrict__ flagp) {
  __shared__ char valb[2 * 16 * 264];
  const int h = blockIdx.x, b = blockIdx.y, w0 = blockIdx.z * 16;
  const int lane = threadIdx.x;
  const int lm = lane & 15, cq = lane >> 4;
  const int wcol = w0 + lm;
  const int g0 = 2 * cq, g1 = 2 * cq + 1;

  f32x4 acc[8];
#pragma unroll
  for (int nt = 0; nt < 8; ++nt) acc[nt] = (f32x4){0.f, 0.f, 0.f, 0.f};

  const float* omr = om + ((long)(b * Hn + h) * CMn << 6);
  const unsigned short* fbb = fupb + ((long)b << 19);   // [pos][128ch]
  const unsigned short* fbA = fbb + g0 * 16;
  const unsigned short* fbB = fbb + g1 * 16;

  union U4 { uint4 q; unsigned short s[8]; };

#pragma unroll
  for (int k = 0; k < Kn; ++k) {
    const int ch0 = g0 * Kn + k, ch1 = g1 * Kn + k;
    // om reads (w-coalesced rows)
    float oyA = omr[(ch0 << 6) + wcol];
    float oxA = omr[((72 + ch0) << 6) + wcol];
    float mkA = omr[((144 + ch0) << 6) + wcol];
    float oyB = omr[(ch1 << 6) + wcol];
    float oxB = omr[((72 + ch1) << 6) + wcol];
    float mkB = omr[((144 + ch1) << 6) + wcol];

    const float bh = (float)(h + k / 3 - 1), bw = (float)(wcol + k % 3 - 1);
    // group A bilinear
    float pyA = bh + oyA, pxA = bw + oxA;
    float fyA = floorf(pyA), fxA = floorf(pxA);
    float lyA = pyA - fyA, lxA = pxA - fxA;
    int y0A = (int)fyA, x0A = (int)fxA, y1A = y0A + 1, x1A = x0A + 1;
    float vy0A = (y0A >= 0 && y0A < Hn) ? 1.f : 0.f;
    float vy1A = (y1A >= 0 && y1A < Hn) ? 1.f : 0.f;
    float vx0A = (x0A >= 0 && x0A < Wn) ? 1.f : 0.f;
    float vx1A = (x1A >= 0 && x1A < Wn) ? 1.f : 0.f;
    int cy0A = min(max(y0A, 0), Hn - 1), cy1A = min(max(y1A, 0), Hn - 1);
    int cx0A = min(max(x0A, 0), Wn - 1), cx1A = min(max(x1A, 0), Wn - 1);
    float wA0 = (1.f - lyA) * (1.f - lxA) * vy0A * vx0A * mkA;
    float wA1 = (1.f - lyA) * lxA * vy0A * vx1A * mkA;
    float wA2 = lyA * (1.f - lxA) * vy1A * vx0A * mkA;
    float wA3 = lyA * lxA * vy1A * vx1A * mkA;
    // group B bilinear
    float pyB = bh + oyB, pxB = bw + oxB;
    float fyB = floorf(pyB), fxB = floorf(pxB);
    float lyB = pyB - fyB, lxB = pxB - fxB;
    int y0B = (int)fyB, x0B = (int)fxB, y1B = y0B + 1, x1B = x0B + 1;
    float vy0B = (y0B >= 0 && y0B < Hn) ? 1.f : 0.f;
    float vy1B = (y1B >= 0 && y1B < Hn) ? 1.f : 0.f;
    float vx0B = (x0B >= 0 && x0B < Wn) ? 1.f : 0.f;
    float vx1B = (x1B >= 0 && x1B < Wn) ? 1.f : 0.f;
    int cy0B = min(max(y0B, 0), Hn - 1), cy1B = min(max(y1B, 0), Hn - 1);
    int cx0B = min(max(x0B, 0), Wn - 1), cx1B = min(max(x1B, 0), Wn - 1);
    float wB0 = (1.f - lyB) * (1.f - lxB) * vy0B * vx0B * mkB;
    float wB1 = (1.f - lyB) * lxB * vy0B * vx1B * mkB;
    float wB2 = lyB * (1.f - lxB) * vy1B * vx0B * mkB;
    float wB3 = lyB * lxB * vy1B * vx1B * mkB;

    // 16 corner loads (4 corners x 2 groups x 32B)
    const unsigned short* qA0 = fbA + ((long)(cy0A * Wn + cx0A) << 7);
    const unsigned short* qA1 = fbA + ((long)(cy0A * Wn + cx1A) << 7);
    const unsigned short* qA2 = fbA + ((long)(cy1A * Wn + cx0A) << 7);
    const unsigned short* qA3 = fbA + ((long)(cy1A * Wn + cx1A) << 7);
    const unsigned short* qB0 = fbB + ((long)(cy0B * Wn + cx0B) << 7);
    const unsigned short* qB1 = fbB + ((long)(cy0B * Wn + cx1B) << 7);
    const unsigned short* qB2 = fbB + ((long)(cy1B * Wn + cx0B) << 7);
    const unsigned short* qB3 = fbB + ((long)(cy1B * Wn + cx1B) << 7);
    U4 a0l, a0h, a1l, a1h, a2l, a2h, a3l, a3h;
    U4 b0l, b0h, b1l, b1h, b2l, b2h, b3l, b3h;
    a0l.q = *(const uint4*)qA0; a0h.q = *(const uint4*)(qA0 + 8);
    a1l.q = *(const uint4*)qA1; a1h.q = *(const uint4*)(qA1 + 8);
    a2l.q = *(const uint4*)qA2; a2h.q = *(const uint4*)(qA2 + 8);
    a3l.q = *(const uint4*)qA3; a3h.q = *(const uint4*)(qA3 + 8);
    b0l.q = *(const uint4*)qB0; b0h.q = *(const uint4*)(qB0 + 8);
    b1l.q = *(const uint4*)qB1; b1h.q = *(const uint4*)(qB1 + 8);
    b2l.q = *(const uint4*)qB2; b2h.q = *(const uint4*)(qB2 + 8);
    b3l.q = *(const uint4*)qB3; b3h.q = *(const uint4*)(qB3 + 8);

    float v[32];
#pragma unroll
    for (int j = 0; j < 8; ++j) {
      v[j]      = wA0 * b2f(a0l.s[j]) + wA1 * b2f(a1l.s[j]) +
                  wA2 * b2f(a2l.s[j]) + wA3 * b2f(a3l.s[j]);
      v[8 + j]  = wA0 * b2f(a0h.s[j]) + wA1 * b2f(a1h.s[j]) +
                  wA2 * b2f(a2h.s[j]) + wA3 * b2f(a3h.s[j]);
      v[16 + j] = wB0 * b2f(b0l.s[j]) + wB1 * b2f(b1l.s[j]) +
                  wB2 * b2f(b2l.s[j]) + wB3 * b2f(b3l.s[j]);
      v[24 + j] = wB0 * b2f(b0h.s[j]) + wB1 * b2f(b1h.s[j]) +
                  wB2 * b2f(b2h.s[j]) + wB3 * b2f(b3h.s[j]);
    }

    char* base = valb + (k & 1) * (16 * 264);
    char* row = base + lm * 264 + cq * 64;
#pragma unroll
    for (int j2 = 0; j2 < 4; ++j2) {
      uint4 pk;
      pk.x = pack2(v[j2 * 8 + 0], v[j2 * 8 + 1]);
      pk.y = pack2(v[j2 * 8 + 2], v[j2 * 8 + 3]);
      pk.z = pack2(v[j2 * 8 + 4], v[j2 * 8 + 5]);
      pk.w = pack2(v[j2 * 8 + 6], v[j2 * 8 + 7]);
      *(uint4*)(row + j2 * 16) = pk;
    }

    // MFMA: same-wave ds_write -> ds_read (lgkmcnt, no barrier)
    const unsigned short* wkb = wdb + (long)k * Cn * Cn;
#pragma unroll
    for (int ks = 0; ks < 4; ++ks) {
      bf16x8 af = *(const bf16x8*)(base + lm * 264 + ks * 64 + cq * 16);
#pragma unroll
      for (int nt = 0; nt < 8; ++nt) {
        bf16x8 bfv = *(const bf16x8*)(wkb + (long)(nt * 16 + lm) * Cn
                                      + ks * 32 + cq * 8);
        acc[nt] = __builtin_amdgcn_mfma_f32_16x16x32_bf16(af, bfv, acc[nt], 0, 0, 0);
      }
    }
  }

  // epilogue: bias, relu, + feat_arm, dtype-branched store
  bool isbf = (*flagp != 0);
#pragma unroll
  for (int nt = 0; nt < 8; ++nt) {
    int o = nt * 16 + lm;
    float bias = bdc[o];
#pragma unroll
    for (int r = 0; r < 4; ++r) {
      int w = w0 + cq * 4 + r;
      long oi = (long)(b * Cn + o) * HWn + h * Wn + w;
      float v = acc[nt][r] + bias;
      v = fmaxf(v, 0.f) + farm[oi];
      if (isbf) ((__hip_bfloat16*)out)[oi] = __float2bfloat16(v);
      else      ((float*)out)[oi] = v;
    }
  }
}

// ---------------- launcher ----------------
extern "C" void kernel_launch(void* const* d_in, const int* in_sizes, int n_in,
                              void* d_out, int out_size, void* d_ws, size_t ws_size,
                              hipStream_t stream) {
  (void)in_sizes; (void)n_in; (void)out_size; (void)ws_size;
  const void* feat_l  = d_in[0];
  const void* feat_s  = d_in[1];
  const void* w_atten = d_in[2];
  const void* w_fsm   = d_in[3];
  const void* w_off   = d_in[4];
  const void* w_cm    = d_in[5];
  const void* b_cm    = d_in[6];
  const void* w_dcn   = d_in[7];
  const void* b_dcn   = d_in[8];
  float* ws = (float*)d_ws;
  int* flagw = (int*)d_ws;
  const int* flag = (const int*)d_ws;
  unsigned short* wdb = (unsigned short*)(ws + OFF_WDT);
  unsigned short* wcb = (unsigned short*)(ws + OFF_WCT);
  unsigned short* oftb = (unsigned short*)(ws + OFF_OFT);
  unsigned short* fupb = (unsigned short*)(ws + OFF_FUPB);

  k_detect<<<1, 256, 0, stream>>>((const unsigned int*)feat_l, flagw);
  k_cvt<<<2048, 256, 0, stream>>>(feat_l, ws + OFF_FL, Bn * Cn * HWn, flag);
  k_cvt<<<512, 256, 0, stream>>>(feat_s, ws + OFF_FS, Bn * Cn * HWs, flag);
  k_cvt<<<1, 256, 0, stream>>>(b_cm, ws + OFF_BCM, CMn, flag);
  k_cvt<<<1, 256, 0, stream>>>(b_dcn, ws + OFF_BDC, Cn, flag);
  k_woffT<<<(2 * Cn * Cn + 255) / 256, 256, 0, stream>>>(w_off, ws + OFF_WOT, flag);
  k_wcmB<<<(18 * 224 * 64 + 255) / 256, 256, 0, stream>>>(w_cm, wcb, flag);
  k_wdcnB<<<(Kn * Cn * Cn + 255) / 256, 256, 0, stream>>>(w_dcn, wdb, flag);
  k_gap<<<Bn * Cn, 256, 0, stream>>>(ws + OFF_FL, ws + OFF_GAP);
  k_atten<<<4, 256, 0, stream>>>(ws + OFF_GAP, w_atten, ws + OFF_AT, flag);
  k_w1t<<<(Bn * Cn * Cn + 255) / 256, 256, 0, stream>>>(w_fsm, ws + OFF_AT, ws + OFF_W1T, flag);
  k_up<<<(Bn * Cn * HWn + 255) / 256, 256, 0, stream>>>(ws + OFF_FS, ws + OFF_FUP);
  k_upb<<<dim3(64, 8), 256, 0, stream>>>(ws + OFF_FUP, fupb);
  k_farm<<<dim3(16, 16, 8), 256, 0, stream>>>(ws + OFF_FL, ws + OFF_W1T, ws + OFF_ARM);
  k_offf<<<dim3(16, 16, 8), 256, 0, stream>>>(ws + OFF_ARM, ws + OFF_FUP, ws + OFF_WOT, oftb);
  k_convcm<<<dim3(64, 8), 256, 0, stream>>>(oftb, wcb, ws + OFF_BCM, ws + OFF_OM);
  k_dcn<<<dim3(64, 8, 4), 64, 0, stream>>>(ws + OFF_OM, fupb, wdb,
                                           ws + OFF_BDC, ws + OFF_ARM, d_out, flag);
}

// Round 8
// 252.340 us; speedup vs baseline: 1.1517x; 1.1517x over previous
//
#include <hip/hip_runtime.h>
#include <hip/hip_bf16.h>

// ---------------- problem constants ----------------
constexpr int Bn = 8, Cn = 128, Hn = 64, Wn = 64, HWn = Hn * Wn;
constexpr int DGn = 8, Kn = 9, CMn = 216;          // CM = DG*3*K
constexpr int Hs = 32, Ws = 32, HWs = Hs * Ws;

typedef __attribute__((ext_vector_type(8))) short bf16x8;
typedef __attribute__((ext_vector_type(4))) float f32x4;

// ---------------- workspace layout (float offsets) ----------------
constexpr long OFF_FLAG = 0;                        // int flag at word 0
constexpr long OFF_FL   = 256;                      // feat_l f32   [8][128][4096]
constexpr long OFF_FS   = OFF_FL  + (long)Bn*Cn*HWn;      // feat_s f32 [8][128][1024]
constexpr long OFF_W1T  = OFF_FS  + (long)Bn*Cn*HWs;      // w1t [b][c][o] 8*128*128
constexpr long OFF_WOT  = OFF_W1T + (long)Bn*Cn*Cn;       // w_offT [c 256][o 128] (2x folded)
constexpr long OFF_WCT  = OFF_WOT + (long)2*Cn*Cn;        // w_cm bf16 slices [18][224][128B-swz]
constexpr long OFF_WDT  = OFF_WCT + (long)Cn*Kn*224;      // w_dcn bf16 [k][o][c]
constexpr long OFF_BCM  = OFF_WDT + (long)Kn*Cn*Cn;       // b_cm (216, padded 256)
constexpr long OFF_BDC  = OFF_BCM + 256;                  // b_dcn (128, padded 256)
constexpr long OFF_GAP  = OFF_BDC + 256;                  // gap [b][c]
constexpr long OFF_AT   = OFF_GAP + (long)Bn*Cn;          // 1+sigmoid(atten) [b][c]
constexpr long OFF_FUP  = OFF_AT  + (long)Bn*Cn;          // feat_up f32 [8][128][4096]
constexpr long OFF_ARM  = OFF_FUP + (long)Bn*Cn*HWn;      // feat_arm f32
constexpr long OFF_OFT  = OFF_ARM + (long)Bn*Cn*HWn;      // off_feat bf16 NHWC [8][4096][128]
constexpr long OFF_OM   = OFF_OFT + (long)Bn*Cn*HWn;      // om f32 [b][h][216][64]
constexpr long OFF_FUPB = OFF_OM  + (long)Bn*CMn*HWn;     // fup bf16 NHWC [8][4096][128]

static __device__ __forceinline__ float ldin(const void* p, long i, bool isbf) {
  if (isbf) return __bfloat162float(((const __hip_bfloat16*)p)[i]);
  return ((const float*)p)[i];
}

// f32 -> bf16 bits (RNE, finite inputs)
static __device__ __forceinline__ unsigned short f2b(float f) {
  unsigned u = __builtin_bit_cast(unsigned, f);
  u += 0x7FFFu + ((u >> 16) & 1u);
  return (unsigned short)(u >> 16);
}
static __device__ __forceinline__ unsigned pack2(float v0, float v1) {
  return ((unsigned)f2b(v1) << 16) | (unsigned)f2b(v0);
}
static __device__ __forceinline__ float b2f(unsigned short s) {
  return __builtin_bit_cast(float, ((unsigned)s) << 16);
}

#define GLOAD_LDS16(g, l) __builtin_amdgcn_global_load_lds( \
    (const __attribute__((address_space(1))) void*)(g),     \
    (__attribute__((address_space(3))) void*)(l), 16, 0, 0)

// ---------------- dtype detector ----------------
__global__ __launch_bounds__(256) void k_detect(const unsigned int* __restrict__ p,
                                                int* __restrict__ flag) {
  __shared__ int cnt[256];
  int t = threadIdx.x;
  int c = 0;
  for (int i = 0; i < 4; ++i) {
    unsigned v = p[t * 4 + i];
    unsigned e = (v >> 7) & 0xFFu;
    c += (e >= 118u && e <= 130u) ? 1 : 0;
  }
  cnt[t] = c;
  __syncthreads();
  for (int s = 128; s > 0; s >>= 1) {
    if (t < s) cnt[t] += cnt[t + s];
    __syncthreads();
  }
  if (t == 0) *flag = (cnt[0] > 512) ? 1 : 0;
}

// ---------------- input conversion ----------------
__global__ __launch_bounds__(256) void k_cvt(const void* __restrict__ src,
                                             float* __restrict__ dst, int n,
                                             const int* __restrict__ flag) {
  int stride = gridDim.x * blockDim.x;
  int i0 = blockIdx.x * blockDim.x + threadIdx.x;
  if (*flag) {
    const __hip_bfloat16* s = (const __hip_bfloat16*)src;
    for (int i = i0; i < n; i += stride) dst[i] = __bfloat162float(s[i]);
  } else {
    const float* s = (const float*)src;
    for (int i = i0; i < n; i += stride) dst[i] = s[i];
  }
}

// w_off [o 128][c 256] -> [c 256][o 128], with 2.0x folded for c>=128
__global__ __launch_bounds__(256) void k_woffT(const void* __restrict__ src,
                                               float* __restrict__ dst,
                                               const int* __restrict__ flag) {
  int i = blockIdx.x * 256 + threadIdx.x;
  if (i >= 2 * Cn * Cn) return;
  int c = i >> 7, o = i & 127;
  bool isbf = (*flag != 0);
  float v = ldin(src, (long)o * 256 + c, isbf);
  if (c >= Cn) v *= 2.0f;
  dst[i] = v;
}

// w_cm [oc 216][c 128][k 9] -> bf16 slices [s 18][oc 224][chunk-swizzled 128B]
__global__ __launch_bounds__(256) void k_wcmB(const void* __restrict__ src,
                                              unsigned short* __restrict__ dst,
                                              const int* __restrict__ flag) {
  int i = blockIdx.x * 256 + threadIdx.x;
  if (i >= 18 * 224 * 64) return;
  int s = i / (224 * 64);
  int rem = i % (224 * 64);
  int oc = rem >> 6;
  int c_off = rem & 63;
  int tap = s >> 1, ck = s & 1;
  int c = ck * 64 + c_off;
  bool isbf = (*flag != 0);
  float v = 0.f;
  if (oc < CMn) v = ldin(src, ((long)oc * Cn + c) * Kn + tap, isbf);
  int chunk = c_off >> 3, e = c_off & 7;
  int pc = chunk ^ (oc & 7);
  dst[(long)s * 14336 + oc * 64 + pc * 8 + e] = f2b(v);
}

// w_dcn [o 128][c 128][k 9] -> bf16 [k][o][c]
__global__ __launch_bounds__(256) void k_wdcnB(const void* __restrict__ src,
                                               unsigned short* __restrict__ dst,
                                               const int* __restrict__ flag) {
  int i = blockIdx.x * 256 + threadIdx.x;
  if (i >= Kn * Cn * Cn) return;
  int k = i / (Cn * Cn);
  int o = (i >> 7) & 127;
  int c = i & 127;
  bool isbf = (*flag != 0);
  float v = ldin(src, ((long)o * Cn + c) * Kn + k, isbf);
  dst[i] = f2b(v);
}

// ---------------- gap ----------------
__global__ __launch_bounds__(256) void k_gap(const float* __restrict__ fl,
                                             float* __restrict__ gap) {
  __shared__ float red[256];
  int bc = blockIdx.x, t = threadIdx.x;
  const float* p = fl + (long)bc * HWn;
  float s = 0.f;
  for (int i = t; i < HWn; i += 256) s += p[i];
  red[t] = s;
  __syncthreads();
  for (int k = 128; k > 0; k >>= 1) {
    if (t < k) red[t] += red[t + k];
    __syncthreads();
  }
  if (t == 0) gap[bc] = red[0] * (1.0f / HWn);
}

// ---------------- atten ----------------
__global__ __launch_bounds__(256) void k_atten(const float* __restrict__ gap,
                                               const void* __restrict__ wat,
                                               float* __restrict__ at1p,
                                               const int* __restrict__ flag) {
  int tid = blockIdx.x * 256 + threadIdx.x;
  if (tid >= Bn * Cn) return;
  int b = tid >> 7, o = tid & 127;
  bool isbf = (*flag != 0);
  const float* g = gap + b * Cn;
  float s = 0.f;
  for (int c = 0; c < Cn; ++c) s += g[c] * ldin(wat, (long)o * Cn + c, isbf);
  at1p[tid] = 1.0f + 1.0f / (1.0f + expf(-s));
}

// w1t[b][c][o] = w_fsm[o][c] * (1 + atten[b][c])
__global__ __launch_bounds__(256) void k_w1t(const void* __restrict__ wfsm,
                                             const float* __restrict__ at1p,
                                             float* __restrict__ dst,
                                             const int* __restrict__ flag) {
  int i = blockIdx.x * 256 + threadIdx.x;
  if (i >= Bn * Cn * Cn) return;
  int b = i >> 14, c = (i >> 7) & 127, o = i & 127;
  bool isbf = (*flag != 0);
  dst[i] = ldin(wfsm, (long)o * Cn + c, isbf) * at1p[b * Cn + c];
}

// ---------------- bilinear 2x upsample (f32 NCHW) ----------------
__global__ __launch_bounds__(256) void k_up(const float* __restrict__ fs,
                                            float* __restrict__ fup) {
  int idx = blockIdx.x * 256 + threadIdx.x;
  if (idx >= Bn * Cn * HWn) return;
  int w = idx & 63, h = (idx >> 6) & 63, bc = idx >> 12;
  const float* s = fs + (long)bc * HWs;
  int iy0; float fy;
  if (h & 1) { iy0 = (h - 1) >> 1; fy = 0.25f; } else { iy0 = (h >> 1) - 1; fy = 0.75f; }
  int ix0; float fx;
  if (w & 1) { ix0 = (w - 1) >> 1; fx = 0.25f; } else { ix0 = (w >> 1) - 1; fx = 0.75f; }
  int iy1 = min(iy0 + 1, Hs - 1); iy0 = max(iy0, 0);
  int ix1 = min(ix0 + 1, Ws - 1); ix0 = max(ix0, 0);
  float v = (1.f - fy) * ((1.f - fx) * s[iy0 * Ws + ix0] + fx * s[iy0 * Ws + ix1]) +
            fy        * ((1.f - fx) * s[iy1 * Ws + ix0] + fx * s[iy1 * Ws + ix1]);
  fup[idx] = v;
}

// ---------------- fup f32 NCHW -> bf16 NHWC transpose ----------------
__global__ __launch_bounds__(256) void k_upb(const float* __restrict__ fup,
                                             unsigned short* __restrict__ fupb) {
  __shared__ float xs[128][65];
  const int b = blockIdx.y, p0 = blockIdx.x * 64, t = threadIdx.x;
  const float* src = fup + (long)b * Cn * HWn + p0;
  for (int i = t; i < 128 * 64; i += 256) {
    int c = i >> 6, p = i & 63;
    xs[c][p] = src[(long)c * HWn + p];
  }
  __syncthreads();
  for (int i = t; i < 1024; i += 256) {
    int p = i >> 4, ch = (i & 15) * 8;
    uint4 pk;
    pk.x = pack2(xs[ch + 0][p], xs[ch + 1][p]);
    pk.y = pack2(xs[ch + 2][p], xs[ch + 3][p]);
    pk.z = pack2(xs[ch + 4][p], xs[ch + 5][p]);
    pk.w = pack2(xs[ch + 6][p], xs[ch + 7][p]);
    *(uint4*)(fupb + (((long)(b * HWn + p0 + p)) << 7) + ch) = pk;
  }
}

// ---------------- feat_arm ----------------
__global__ __launch_bounds__(256) void k_farm(const float* __restrict__ fl,
                                              const float* __restrict__ w1t,
                                              float* __restrict__ farm) {
  const int t = threadIdx.x;
  const int b = blockIdx.z, og = blockIdx.y;
  const int pos = blockIdx.x * 256 + t;
  const float* x = fl + (long)b * Cn * HWn + pos;
  const float* wb = w1t + (long)b * Cn * Cn + og * 8;
  float acc[8];
#pragma unroll
  for (int o = 0; o < 8; ++o) acc[o] = 0.f;
  for (int c = 0; c < Cn; ++c) {
    float xv = x[(long)c * HWn];
    const float4* w4 = (const float4*)(wb + (long)c * Cn);
    float4 wa = w4[0], wc = w4[1];
    acc[0] += xv * wa.x; acc[1] += xv * wa.y; acc[2] += xv * wa.z; acc[3] += xv * wa.w;
    acc[4] += xv * wc.x; acc[5] += xv * wc.y; acc[6] += xv * wc.z; acc[7] += xv * wc.w;
  }
#pragma unroll
  for (int o = 0; o < 8; ++o)
    farm[(long)(b * Cn + og * 8 + o) * HWn + pos] = acc[o];
}

// ---------------- off_feat -> bf16 NHWC [b][pos][c] ----------------
__global__ __launch_bounds__(256) void k_offf(const float* __restrict__ arm,
                                              const float* __restrict__ fup,
                                              const float* __restrict__ wot,
                                              unsigned short* __restrict__ oftb) {
  const int t = threadIdx.x;
  const int b = blockIdx.z, og = blockIdx.y;
  const int pos = blockIdx.x * 256 + t;
  const float* xa = arm + (long)b * Cn * HWn + pos;
  const float* xu = fup + (long)b * Cn * HWn + pos;
  const float* wg = wot + og * 8;
  float acc[8];
#pragma unroll
  for (int o = 0; o < 8; ++o) acc[o] = 0.f;
  for (int c = 0; c < Cn; ++c) {
    float xv = xa[(long)c * HWn];
    const float4* w4 = (const float4*)(wg + (long)c * Cn);
    float4 wa = w4[0], wc = w4[1];
    acc[0] += xv * wa.x; acc[1] += xv * wa.y; acc[2] += xv * wa.z; acc[3] += xv * wa.w;
    acc[4] += xv * wc.x; acc[5] += xv * wc.y; acc[6] += xv * wc.z; acc[7] += xv * wc.w;
  }
  for (int c = 0; c < Cn; ++c) {
    float xv = xu[(long)c * HWn];
    const float4* w4 = (const float4*)(wg + (long)(Cn + c) * Cn);
    float4 wa = w4[0], wc = w4[1];
    acc[0] += xv * wa.x; acc[1] += xv * wa.y; acc[2] += xv * wa.z; acc[3] += xv * wa.w;
    acc[4] += xv * wc.x; acc[5] += xv * wc.y; acc[6] += xv * wc.z; acc[7] += xv * wc.w;
  }
  uint4 pk;
  pk.x = pack2(acc[0], acc[1]); pk.y = pack2(acc[2], acc[3]);
  pk.z = pack2(acc[4], acc[5]); pk.w = pack2(acc[6], acc[7]);
  *(uint4*)(oftb + (((long)b * HWn + pos) << 7) + og * 8) = pk;
}

// ---------------- 3x3 conv via bf16 MFMA, LDS-staged weights -> om ----------------
// om output layout: [b][h][216][64] (w-contiguous rows for k_dcn coalescing).
__global__ __launch_bounds__(256) void k_convcm(const unsigned short* __restrict__ xb,
                                                const unsigned short* __restrict__ wsl,
                                                const float* __restrict__ bcm,
                                                float* __restrict__ om) {
  __shared__ unsigned short wlds[2][14336];   // 2 x 28,672 B
  const int h = blockIdx.x, b = blockIdx.y;
  const int t = threadIdx.x, lane = t & 63, wv = t >> 6;
  const int mi = wv & 1, ni = wv >> 1;
  const int lm = lane & 15, lh = lane >> 4;

  f32x4 acc[2][7];
#pragma unroll
  for (int mt = 0; mt < 2; ++mt)
#pragma unroll
    for (int nt = 0; nt < 7; ++nt) acc[mt][nt] = (f32x4){0.f, 0.f, 0.f, 0.f};

  auto stage = [&](int s, int bufi) {
    const char* src = (const char*)(wsl + (long)s * 14336);
    char* dstb = (char*)&wlds[bufi][0];
#pragma unroll
    for (int i2 = 0; i2 < 7; ++i2) {
      int off = (wv * 7 + i2) * 1024;
      GLOAD_LDS16(src + off + lane * 16, dstb + off);
    }
  };

  stage(0, 0);
  __syncthreads();

  for (int s = 0; s < 18; ++s) {
    const int cur = s & 1;
    if (s < 17) stage(s + 1, cur ^ 1);
    const int tap = s >> 1, ck = s & 1;
    const int ky = tap / 3, kx = tap % 3;
    const int gy = h + ky - 1;
    const bool gyok = ((unsigned)gy < (unsigned)Hn);
    const int gyc = min(max(gy, 0), Hn - 1);

    bf16x8 af[2][2];
#pragma unroll
    for (int mt = 0; mt < 2; ++mt) {
      int wpos = mi * 32 + mt * 16 + lm;
      int gx = wpos + kx - 1;
      bool ok = gyok && ((unsigned)gx < (unsigned)Wn);
      int gxc = min(max(gx, 0), Wn - 1);
      const unsigned short* ap = xb + (((long)(b * HWn + gyc * Wn + gxc)) << 7)
                                    + ck * 64 + lh * 8;
#pragma unroll
      for (int ksub = 0; ksub < 2; ++ksub) {
        bf16x8 v = *(const bf16x8*)(ap + ksub * 32);
        af[mt][ksub] = ok ? v : (bf16x8)(short)0;
      }
    }

    const char* wbase = (const char*)&wlds[cur][0];
#pragma unroll
    for (int ksub = 0; ksub < 2; ++ksub) {
      int jj = ksub * 4 + lh;
#pragma unroll
      for (int nt = 0; nt < 7; ++nt) {
        int oc = ni * 112 + nt * 16 + lm;
        bf16x8 bfv = *(const bf16x8*)(wbase + oc * 128 + ((jj ^ (oc & 7)) << 4));
#pragma unroll
        for (int mt = 0; mt < 2; ++mt)
          acc[mt][nt] = __builtin_amdgcn_mfma_f32_16x16x32_bf16(
              af[mt][ksub], bfv, acc[mt][nt], 0, 0, 0);
      }
    }
    __syncthreads();
  }

#pragma unroll
  for (int nt = 0; nt < 7; ++nt) {
    int ch = ni * 112 + nt * 16 + lm;
    if (ch >= CMn) continue;
    float bias = bcm[ch];
#pragma unroll
    for (int mt = 0; mt < 2; ++mt) {
#pragma unroll
      for (int r = 0; r < 4; ++r) {
        int w = mi * 32 + mt * 16 + lh * 4 + r;
        float v = acc[mt][nt][r] + bias;
        if (ch >= 144) v = 1.0f / (1.0f + expf(-v));
        om[((long)((b * Hn + h) * CMn + ch) << 6) + w] = v;
      }
    }
  }
}

// ---------------- fused DCN v2: 8-wave, tap-parity dbuf, 1 barrier/tap ----------------
// Block (h, b, w-half=32): 512 threads = 8 waves.
// Gather role: worker = t&255 -> (gw = t&31, g = (t>>5)&7), half = t>>8 owns
//   8 of the group's 16 channels (4 corner uint4 loads).
// MFMA role: wave wid owns o-slice [wid*16, wid*16+16): acc[2] (M=32 x N=16).
// Double-buffered val by tap parity: ONE barrier per tap is sufficient —
//   read(k-1)[buf p] precedes barrier(k) in program order, write(k+1)[buf p]
//   follows barrier(k), so the hazard is barrier-separated.
__global__ __launch_bounds__(512, 6) void k_dcn(const float* __restrict__ om,
                                                const unsigned short* __restrict__ fupb,
                                                const unsigned short* __restrict__ wdb,
                                                const float* __restrict__ bdc,
                                                const float* __restrict__ farm,
                                                void* __restrict__ out,
                                                const int* __restrict__ flagp) {
  __shared__ char valb[2][32 * 272];
  const int h = blockIdx.x, b = blockIdx.y, w0 = blockIdx.z * 32;
  const int t = threadIdx.x;
  const int lane = t & 63, wid = t >> 6;
  const int lm = lane & 15, lh = lane >> 4;
  const int gw = t & 31, g = (t >> 5) & 7, half = t >> 8;

  f32x4 acc[2];
  acc[0] = (f32x4){0.f, 0.f, 0.f, 0.f};
  acc[1] = (f32x4){0.f, 0.f, 0.f, 0.f};

  const float* omr = om + ((long)(b * Hn + h) * CMn << 6);
  const unsigned short* fb = fupb + ((long)b << 19) + g * 16 + half * 8;
  const int wcol = w0 + gw;

  union U4 { uint4 q; unsigned short s[8]; };

#pragma unroll
  for (int k = 0; k < Kn; ++k) {
    // ---- gather phase: bilinear sample 8 channels of (g, wcol) ----
    int ch = g * Kn + k;
    float oy = omr[(ch << 6) + wcol];
    float ox = omr[((72 + ch) << 6) + wcol];
    float mk = omr[((144 + ch) << 6) + wcol];
    float py = (float)(h + k / 3 - 1) + oy;
    float px = (float)(wcol + k % 3 - 1) + ox;
    float fy = floorf(py), fx = floorf(px);
    float ly = py - fy, lx = px - fx;
    int y0 = (int)fy, x0 = (int)fx, y1 = y0 + 1, x1 = x0 + 1;
    float vy0 = (y0 >= 0 && y0 < Hn) ? 1.f : 0.f;
    float vy1 = (y1 >= 0 && y1 < Hn) ? 1.f : 0.f;
    float vx0 = (x0 >= 0 && x0 < Wn) ? 1.f : 0.f;
    float vx1 = (x1 >= 0 && x1 < Wn) ? 1.f : 0.f;
    int cy0 = min(max(y0, 0), Hn - 1), cy1 = min(max(y1, 0), Hn - 1);
    int cx0 = min(max(x0, 0), Wn - 1), cx1 = min(max(x1, 0), Wn - 1);
    float wq0 = (1.f - ly) * (1.f - lx) * vy0 * vx0 * mk;
    float wq1 = (1.f - ly) * lx * vy0 * vx1 * mk;
    float wq2 = ly * (1.f - lx) * vy1 * vx0 * mk;
    float wq3 = ly * lx * vy1 * vx1 * mk;
    U4 c0v, c1v, c2v, c3v;
    c0v.q = *(const uint4*)(fb + ((long)(cy0 * Wn + cx0) << 7));
    c1v.q = *(const uint4*)(fb + ((long)(cy0 * Wn + cx1) << 7));
    c2v.q = *(const uint4*)(fb + ((long)(cy1 * Wn + cx0) << 7));
    c3v.q = *(const uint4*)(fb + ((long)(cy1 * Wn + cx1) << 7));
    float v[8];
#pragma unroll
    for (int j = 0; j < 8; ++j)
      v[j] = wq0 * b2f(c0v.s[j]) + wq1 * b2f(c1v.s[j]) +
             wq2 * b2f(c2v.s[j]) + wq3 * b2f(c3v.s[j]);
    uint4 pk;
    pk.x = pack2(v[0], v[1]); pk.y = pack2(v[2], v[3]);
    pk.z = pack2(v[4], v[5]); pk.w = pack2(v[6], v[7]);
    *(uint4*)(valb[k & 1] + gw * 272 + g * 32 + half * 16) = pk;
    __syncthreads();

    // ---- MFMA phase: acc += val[w][c] * wdb[k][o][c] ----
    const char* base = valb[k & 1];
    const unsigned short* wkb = wdb + (long)k * Cn * Cn + (long)(wid * 16 + lm) * Cn;
#pragma unroll
    for (int ks = 0; ks < 4; ++ks) {
      bf16x8 af0 = *(const bf16x8*)(base + lm * 272 + ks * 64 + lh * 16);
      bf16x8 af1 = *(const bf16x8*)(base + (16 + lm) * 272 + ks * 64 + lh * 16);
      bf16x8 bfv = *(const bf16x8*)(wkb + ks * 32 + lh * 8);
      acc[0] = __builtin_amdgcn_mfma_f32_16x16x32_bf16(af0, bfv, acc[0], 0, 0, 0);
      acc[1] = __builtin_amdgcn_mfma_f32_16x16x32_bf16(af1, bfv, acc[1], 0, 0, 0);
    }
  }

  // ---- epilogue: bias, relu, + feat_arm, dtype-branched store ----
  bool isbf = (*flagp != 0);
  const int o = wid * 16 + lm;
  const float bias = bdc[o];
#pragma unroll
  for (int mt = 0; mt < 2; ++mt) {
#pragma unroll
    for (int r = 0; r < 4; ++r) {
      int w = w0 + mt * 16 + lh * 4 + r;
      long oi = (long)(b * Cn + o) * HWn + h * Wn + w;
      float v = acc[mt][r] + bias;
      v = fmaxf(v, 0.f) + farm[oi];
      if (isbf) ((__hip_bfloat16*)out)[oi] = __float2bfloat16(v);
      else      ((float*)out)[oi] = v;
    }
  }
}

// ---------------- launcher ----------------
extern "C" void kernel_launch(void* const* d_in, const int* in_sizes, int n_in,
                              void* d_out, int out_size, void* d_ws, size_t ws_size,
                              hipStream_t stream) {
  (void)in_sizes; (void)n_in; (void)out_size; (void)ws_size;
  const void* feat_l  = d_in[0];
  const void* feat_s  = d_in[1];
  const void* w_atten = d_in[2];
  const void* w_fsm   = d_in[3];
  const void* w_off   = d_in[4];
  const void* w_cm    = d_in[5];
  const void* b_cm    = d_in[6];
  const void* w_dcn   = d_in[7];
  const void* b_dcn   = d_in[8];
  float* ws = (float*)d_ws;
  int* flagw = (int*)d_ws;
  const int* flag = (const int*)d_ws;
  unsigned short* wdb = (unsigned short*)(ws + OFF_WDT);
  unsigned short* wcb = (unsigned short*)(ws + OFF_WCT);
  unsigned short* oftb = (unsigned short*)(ws + OFF_OFT);
  unsigned short* fupb = (unsigned short*)(ws + OFF_FUPB);

  k_detect<<<1, 256, 0, stream>>>((const unsigned int*)feat_l, flagw);
  k_cvt<<<2048, 256, 0, stream>>>(feat_l, ws + OFF_FL, Bn * Cn * HWn, flag);
  k_cvt<<<512, 256, 0, stream>>>(feat_s, ws + OFF_FS, Bn * Cn * HWs, flag);
  k_cvt<<<1, 256, 0, stream>>>(b_cm, ws + OFF_BCM, CMn, flag);
  k_cvt<<<1, 256, 0, stream>>>(b_dcn, ws + OFF_BDC, Cn, flag);
  k_woffT<<<(2 * Cn * Cn + 255) / 256, 256, 0, stream>>>(w_off, ws + OFF_WOT, flag);
  k_wcmB<<<(18 * 224 * 64 + 255) / 256, 256, 0, stream>>>(w_cm, wcb, flag);
  k_wdcnB<<<(Kn * Cn * Cn + 255) / 256, 256, 0, stream>>>(w_dcn, wdb, flag);
  k_gap<<<Bn * Cn, 256, 0, stream>>>(ws + OFF_FL, ws + OFF_GAP);
  k_atten<<<4, 256, 0, stream>>>(ws + OFF_GAP, w_atten, ws + OFF_AT, flag);
  k_w1t<<<(Bn * Cn * Cn + 255) / 256, 256, 0, stream>>>(w_fsm, ws + OFF_AT, ws + OFF_W1T, flag);
  k_up<<<(Bn * Cn * HWn + 255) / 256, 256, 0, stream>>>(ws + OFF_FS, ws + OFF_FUP);
  k_upb<<<dim3(64, 8), 256, 0, stream>>>(ws + OFF_FUP, fupb);
  k_farm<<<dim3(16, 16, 8), 256, 0, stream>>>(ws + OFF_FL, ws + OFF_W1T, ws + OFF_ARM);
  k_offf<<<dim3(16, 16, 8), 256, 0, stream>>>(ws + OFF_ARM, ws + OFF_FUP, ws + OFF_WOT, oftb);
  k_convcm<<<dim3(64, 8), 256, 0, stream>>>(oftb, wcb, ws + OFF_BCM, ws + OFF_OM);
  k_dcn<<<dim3(64, 8, 2), 512, 0, stream>>>(ws + OFF_OM, fupb, wdb,
                                            ws + OFF_BDC, ws + OFF_ARM, d_out, flag);
}

// Round 9
// 250.179 us; speedup vs baseline: 1.1616x; 1.0086x over previous
//
#include <hip/hip_runtime.h>
#include <hip/hip_bf16.h>

// ---------------- problem constants ----------------
constexpr int Bn = 8, Cn = 128, Hn = 64, Wn = 64, HWn = Hn * Wn;
constexpr int DGn = 8, Kn = 9, CMn = 216;          // CM = DG*3*K
constexpr int Hs = 32, Ws = 32, HWs = Hs * Ws;

typedef __attribute__((ext_vector_type(8))) short bf16x8;
typedef __attribute__((ext_vector_type(4))) float f32x4;

// ---------------- workspace layout (float offsets) ----------------
constexpr long OFF_FLAG = 0;                              // int flag (256 floats)
constexpr long OFF_FLB  = 256;                            // feat_l bf16 NHWC [8][4096][128]
constexpr long OFF_FUPB = OFF_FLB  + (long)Bn*HWn*Cn/2;   // fup bf16 NHWC
constexpr long OFF_OFT  = OFF_FUPB + (long)Bn*HWn*Cn/2;   // off_feat bf16 NHWC
constexpr long OFF_WCT  = OFF_OFT  + (long)Bn*HWn*Cn/2;   // w_cm bf16 slices [18][224][128B-swz]
constexpr long OFF_WDT  = OFF_WCT  + (long)18*224*64/2 + 64;  // w_dcn bf16 [k][o][c]
constexpr long OFF_P    = OFF_WDT  + (long)Kn*Cn*Cn/2 + 64;   // P f32 [128][128]
constexpr long OFF_W1TB = OFF_P    + 16384;               // w1tb bf16 [b][o][c]
constexpr long OFF_WCAT = OFF_W1TB + (long)Bn*Cn*Cn/2;    // wcat bf16 [b][o][256]
constexpr long OFF_BCM  = OFF_WCAT + (long)Bn*Cn*256/2;   // b_cm f32 (256)
constexpr long OFF_BDC  = OFF_BCM + 256;                  // b_dcn f32 (256)
constexpr long OFF_GAP  = OFF_BDC + 256;                  // gap f32 [b][c] (1024)
constexpr long OFF_AT   = OFF_GAP + 1024;                 // 1+sigmoid(atten) (1024)
constexpr long OFF_FARM = OFF_AT  + 1024;                 // feat_arm f32 NCHW [8][128][4096]
constexpr long OFF_OM   = OFF_FARM + (long)Bn*Cn*HWn;     // om f32 [b][h][216][64]
// total ~ 18.0M floats ~ 72 MiB

static __device__ __forceinline__ float ldin(const void* p, long i, bool isbf) {
  if (isbf) return __bfloat162float(((const __hip_bfloat16*)p)[i]);
  return ((const float*)p)[i];
}
static __device__ __forceinline__ unsigned short f2b(float f) {
  unsigned u = __builtin_bit_cast(unsigned, f);
  u += 0x7FFFu + ((u >> 16) & 1u);
  return (unsigned short)(u >> 16);
}
static __device__ __forceinline__ unsigned pack2(float v0, float v1) {
  return ((unsigned)f2b(v1) << 16) | (unsigned)f2b(v0);
}
static __device__ __forceinline__ float b2f(unsigned short s) {
  return __builtin_bit_cast(float, ((unsigned)s) << 16);
}

#define GLOAD_LDS16(g, l) __builtin_amdgcn_global_load_lds( \
    (const __attribute__((address_space(1))) void*)(g),     \
    (__attribute__((address_space(3))) void*)(l), 16, 0, 0)

// ---------------- dtype detector ----------------
__global__ __launch_bounds__(256) void k_detect(const unsigned int* __restrict__ p,
                                                int* __restrict__ flag) {
  __shared__ int cnt[256];
  int t = threadIdx.x;
  int c = 0;
  for (int i = 0; i < 4; ++i) {
    unsigned v = p[t * 4 + i];
    unsigned e = (v >> 7) & 0xFFu;
    c += (e >= 118u && e <= 130u) ? 1 : 0;
  }
  cnt[t] = c;
  __syncthreads();
  for (int s = 128; s > 0; s >>= 1) {
    if (t < s) cnt[t] += cnt[t + s];
    __syncthreads();
  }
  if (t == 0) *flag = (cnt[0] > 512) ? 1 : 0;
}

// ---------------- small f32 conversions (biases) ----------------
__global__ __launch_bounds__(256) void k_cvt(const void* __restrict__ src,
                                             float* __restrict__ dst, int n,
                                             const int* __restrict__ flag) {
  int i = blockIdx.x * 256 + threadIdx.x;
  if (i >= n) return;
  dst[i] = ldin(src, i, *flag != 0);
}

// ---------------- feat_l -> flb bf16 NHWC ----------------
__global__ __launch_bounds__(256) void k_cvtl(const void* __restrict__ src,
                                              unsigned short* __restrict__ flb,
                                              const int* __restrict__ flag) {
  __shared__ float xs[128][65];
  const int b = blockIdx.y, p0 = blockIdx.x * 64, t = threadIdx.x;
  bool isbf = (*flag != 0);
  for (int i = t; i < 8192; i += 256) {
    int c = i >> 6, p = i & 63;
    xs[c][p] = ldin(src, (long)(b * Cn + c) * HWn + p0 + p, isbf);
  }
  __syncthreads();
  for (int i = t; i < 1024; i += 256) {
    int p = i >> 4, ch = (i & 15) * 8;
    uint4 pk;
    pk.x = pack2(xs[ch + 0][p], xs[ch + 1][p]);
    pk.y = pack2(xs[ch + 2][p], xs[ch + 3][p]);
    pk.z = pack2(xs[ch + 4][p], xs[ch + 5][p]);
    pk.w = pack2(xs[ch + 6][p], xs[ch + 7][p]);
    *(uint4*)(flb + (((long)(b * HWn + p0 + p)) << 7) + ch) = pk;
  }
}

// ---------------- feat_s -> fupb bf16 NHWC (fused upsample+transpose) ----------------
__global__ __launch_bounds__(256) void k_upbf(const void* __restrict__ fs,
                                              unsigned short* __restrict__ fupb,
                                              const int* __restrict__ flag) {
  __shared__ float L[2][128][33];
  const int b = blockIdx.y, h = blockIdx.x, t = threadIdx.x;
  bool isbf = (*flag != 0);
  int iy0; float fy;
  if (h & 1) { iy0 = (h - 1) >> 1; fy = 0.25f; } else { iy0 = (h >> 1) - 1; fy = 0.75f; }
  int iy1 = min(iy0 + 1, Hs - 1); iy0 = max(iy0, 0);
  for (int i = t; i < 8192; i += 256) {
    int sel = i >> 12, c = (i >> 5) & 127, x = i & 31;
    int iy = sel ? iy1 : iy0;
    L[sel][c][x] = ldin(fs, (long)(b * Cn + c) * HWs + iy * Ws + x, isbf);
  }
  __syncthreads();
  for (int i = t; i < 1024; i += 256) {
    int w = i >> 4, ch0 = (i & 15) * 8;
    int ix0; float fx;
    if (w & 1) { ix0 = (w - 1) >> 1; fx = 0.25f; } else { ix0 = (w >> 1) - 1; fx = 0.75f; }
    int ix1 = min(ix0 + 1, Ws - 1); ix0 = max(ix0, 0);
    float v[8];
#pragma unroll
    for (int j = 0; j < 8; ++j) {
      int c = ch0 + j;
      v[j] = (1.f - fy) * ((1.f - fx) * L[0][c][ix0] + fx * L[0][c][ix1]) +
             fy         * ((1.f - fx) * L[1][c][ix0] + fx * L[1][c][ix1]);
    }
    uint4 pk;
    pk.x = pack2(v[0], v[1]); pk.y = pack2(v[2], v[3]);
    pk.z = pack2(v[4], v[5]); pk.w = pack2(v[6], v[7]);
    *(uint4*)(fupb + (((long)(b * HWn + h * Wn + w)) << 7) + ch0) = pk;
  }
}

// ---------------- gap: partial sums + atomic (gap pre-zeroed) ----------------
__global__ __launch_bounds__(256) void k_gap2(const unsigned short* __restrict__ flb,
                                              float* __restrict__ gap) {
  __shared__ float red[256];
  const int b = blockIdx.x, sl = blockIdx.y;
  const int t = threadIdx.x, c = t & 127, half = t >> 7;
  const unsigned short* p = flb + ((long)b << 19) + (((long)(sl * 512 + half * 256)) << 7) + c;
  float s = 0.f;
#pragma unroll 4
  for (int i = 0; i < 256; ++i) s += b2f(p[(long)i << 7]);
  red[t] = s;
  __syncthreads();
  if (t < 128) atomicAdd(&gap[b * Cn + t], (red[t] + red[t + 128]) * (1.0f / HWn));
}

// ---------------- atten ----------------
__global__ __launch_bounds__(256) void k_atten(const float* __restrict__ gap,
                                               const void* __restrict__ wat,
                                               float* __restrict__ at1p,
                                               const int* __restrict__ flag) {
  int tid = blockIdx.x * 256 + threadIdx.x;
  if (tid >= Bn * Cn) return;
  int b = tid >> 7, o = tid & 127;
  bool isbf = (*flag != 0);
  const float* g = gap + b * Cn;
  float s = 0.f;
  for (int c = 0; c < Cn; ++c) s += g[c] * ldin(wat, (long)o * Cn + c, isbf);
  at1p[tid] = 1.0f + 1.0f / (1.0f + expf(-s));
}

// ---------------- P[o][k] = sum_c w_off[o][c] * w_fsm[c][k] ----------------
__global__ __launch_bounds__(256) void k_pmat(const void* __restrict__ woff,
                                              const void* __restrict__ wfsm,
                                              float* __restrict__ P,
                                              const int* __restrict__ flag) {
  int idx = blockIdx.x * 256 + threadIdx.x;
  if (idx >= Cn * Cn) return;
  int o = idx >> 7, k = idx & 127;
  bool isbf = (*flag != 0);
  float s = 0.f;
  for (int c = 0; c < Cn; ++c)
    s += ldin(woff, (long)o * 256 + c, isbf) * ldin(wfsm, (long)c * Cn + k, isbf);
  P[idx] = s;
}

// ---------------- per-batch weight prep: w1tb [b][o][c], wcat [b][o][256] ----------------
__global__ __launch_bounds__(256) void k_wprep(const void* __restrict__ wfsm,
                                               const void* __restrict__ woff,
                                               const float* __restrict__ P,
                                               const float* __restrict__ at1p,
                                               unsigned short* __restrict__ w1tb,
                                               unsigned short* __restrict__ wcat,
                                               const int* __restrict__ flag) {
  int idx = blockIdx.x * 256 + threadIdx.x;
  if (idx >= Bn * 49152) return;
  bool isbf = (*flag != 0);
  int b = idx / 49152, r = idx % 49152;
  if (r < 16384) {
    int o = r >> 7, k = r & 127;
    w1tb[((long)(b * Cn + o) << 7) + k] =
        f2b(ldin(wfsm, (long)o * Cn + k, isbf) * at1p[b * Cn + k]);
  } else {
    r -= 16384;
    int o = r >> 8, k = r & 255;
    float v = (k < 128) ? P[o * Cn + k] * at1p[b * Cn + k]
                        : 2.0f * ldin(woff, (long)o * 256 + k, isbf);
    wcat[((long)(b * Cn + o) << 8) + k] = f2b(v);
  }
}

// ---------------- w_cm -> bf16 slices [18][224][128B chunk-swizzled] ----------------
__global__ __launch_bounds__(256) void k_wcmB(const void* __restrict__ src,
                                              unsigned short* __restrict__ dst,
                                              const int* __restrict__ flag) {
  int i = blockIdx.x * 256 + threadIdx.x;
  if (i >= 18 * 224 * 64) return;
  int s = i / (224 * 64);
  int rem = i % (224 * 64);
  int oc = rem >> 6;
  int c_off = rem & 63;
  int tap = s >> 1, ck = s & 1;
  int c = ck * 64 + c_off;
  bool isbf = (*flag != 0);
  float v = 0.f;
  if (oc < CMn) v = ldin(src, ((long)oc * Cn + c) * Kn + tap, isbf);
  int chunk = c_off >> 3, e = c_off & 7;
  int pc = chunk ^ (oc & 7);
  dst[(long)s * 14336 + oc * 64 + pc * 8 + e] = f2b(v);
}

// ---------------- w_dcn -> bf16 [k][o][c] ----------------
__global__ __launch_bounds__(256) void k_wdcnB(const void* __restrict__ src,
                                               unsigned short* __restrict__ dst,
                                               const int* __restrict__ flag) {
  int i = blockIdx.x * 256 + threadIdx.x;
  if (i >= Kn * Cn * Cn) return;
  int k = i / (Cn * Cn);
  int o = (i >> 7) & 127;
  int c = i & 127;
  bool isbf = (*flag != 0);
  dst[i] = f2b(ldin(src, ((long)o * Cn + c) * Kn + k, isbf));
}

// ---------------- feat_arm via MFMA: flb x w1tb -> farm f32 NCHW ----------------
__global__ __launch_bounds__(256) void k_farm(const unsigned short* __restrict__ flb,
                                              const unsigned short* __restrict__ w1tb,
                                              float* __restrict__ farm) {
  const int b = blockIdx.y, m0 = blockIdx.x * 64;
  const int t = threadIdx.x, lane = t & 63, wv = t >> 6;
  const int lm = lane & 15, lh = lane >> 4;
  f32x4 acc[4][2];
#pragma unroll
  for (int mt = 0; mt < 4; ++mt)
#pragma unroll
    for (int nt = 0; nt < 2; ++nt) acc[mt][nt] = (f32x4){0.f, 0.f, 0.f, 0.f};
  const unsigned short* A = flb + ((long)b << 19);
  const unsigned short* Bw = w1tb + ((long)b << 14);
#pragma unroll
  for (int ks = 0; ks < 4; ++ks) {
    int c0 = ks * 32 + lh * 8;
    bf16x8 bfv[2];
#pragma unroll
    for (int nt = 0; nt < 2; ++nt)
      bfv[nt] = *(const bf16x8*)(Bw + (long)(wv * 32 + nt * 16 + lm) * Cn + c0);
#pragma unroll
    for (int mt = 0; mt < 4; ++mt) {
      bf16x8 af = *(const bf16x8*)(A + (((long)(m0 + mt * 16 + lm)) << 7) + c0);
#pragma unroll
      for (int nt = 0; nt < 2; ++nt)
        acc[mt][nt] = __builtin_amdgcn_mfma_f32_16x16x32_bf16(af, bfv[nt], acc[mt][nt], 0, 0, 0);
    }
  }
#pragma unroll
  for (int nt = 0; nt < 2; ++nt) {
    int o = wv * 32 + nt * 16 + lm;
#pragma unroll
    for (int mt = 0; mt < 4; ++mt)
      *(f32x4*)(farm + (((long)(b * Cn + o)) << 12) + m0 + mt * 16 + lh * 4) = acc[mt][nt];
  }
}

// ---------------- off_feat via MFMA: [flb|fupb] x wcat -> oftb bf16 NHWC ----------------
__global__ __launch_bounds__(256) void k_offf(const unsigned short* __restrict__ flb,
                                              const unsigned short* __restrict__ fupb,
                                              const unsigned short* __restrict__ wcat,
                                              unsigned short* __restrict__ oftb) {
  const int b = blockIdx.y, m0 = blockIdx.x * 64;
  const int t = threadIdx.x, lane = t & 63, wv = t >> 6;
  const int lm = lane & 15, lh = lane >> 4;
  f32x4 acc[4][2];
#pragma unroll
  for (int mt = 0; mt < 4; ++mt)
#pragma unroll
    for (int nt = 0; nt < 2; ++nt) acc[mt][nt] = (f32x4){0.f, 0.f, 0.f, 0.f};
  const unsigned short* A0 = flb + ((long)b << 19);
  const unsigned short* A1 = fupb + ((long)b << 19);
  const unsigned short* Bw = wcat + ((long)b << 15);
#pragma unroll
  for (int ks = 0; ks < 8; ++ks) {
    int c0 = ks * 32 + lh * 8;                 // [0,256)
    const unsigned short* Asrc = (ks < 4) ? A0 : A1;
    int ca = (ks < 4) ? c0 : (c0 - 128);
    bf16x8 bfv[2];
#pragma unroll
    for (int nt = 0; nt < 2; ++nt)
      bfv[nt] = *(const bf16x8*)(Bw + (((long)(wv * 32 + nt * 16 + lm)) << 8) + c0);
#pragma unroll
    for (int mt = 0; mt < 4; ++mt) {
      bf16x8 af = *(const bf16x8*)(Asrc + (((long)(m0 + mt * 16 + lm)) << 7) + ca);
#pragma unroll
      for (int nt = 0; nt < 2; ++nt)
        acc[mt][nt] = __builtin_amdgcn_mfma_f32_16x16x32_bf16(af, bfv[nt], acc[mt][nt], 0, 0, 0);
    }
  }
#pragma unroll
  for (int nt = 0; nt < 2; ++nt) {
    int o = wv * 32 + nt * 16 + lm;
#pragma unroll
    for (int mt = 0; mt < 4; ++mt)
#pragma unroll
      for (int r = 0; r < 4; ++r)
        oftb[(((long)(b * HWn + m0 + mt * 16 + lh * 4 + r)) << 7) + o] = f2b(acc[mt][nt][r]);
  }
}

// ---------------- 3x3 conv via bf16 MFMA, LDS-staged weights -> om ----------------
__global__ __launch_bounds__(256) void k_convcm(const unsigned short* __restrict__ xb,
                                                const unsigned short* __restrict__ wsl,
                                                const float* __restrict__ bcm,
                                                float* __restrict__ om) {
  __shared__ unsigned short wlds[2][14336];
  const int h = blockIdx.x, b = blockIdx.y;
  const int t = threadIdx.x, lane = t & 63, wv = t >> 6;
  const int mi = wv & 1, ni = wv >> 1;
  const int lm = lane & 15, lh = lane >> 4;

  f32x4 acc[2][7];
#pragma unroll
  for (int mt = 0; mt < 2; ++mt)
#pragma unroll
    for (int nt = 0; nt < 7; ++nt) acc[mt][nt] = (f32x4){0.f, 0.f, 0.f, 0.f};

  auto stage = [&](int s, int bufi) {
    const char* src = (const char*)(wsl + (long)s * 14336);
    char* dstb = (char*)&wlds[bufi][0];
#pragma unroll
    for (int i2 = 0; i2 < 7; ++i2) {
      int off = (wv * 7 + i2) * 1024;
      GLOAD_LDS16(src + off + lane * 16, dstb + off);
    }
  };

  stage(0, 0);
  __syncthreads();

  for (int s = 0; s < 18; ++s) {
    const int cur = s & 1;
    if (s < 17) stage(s + 1, cur ^ 1);
    const int tap = s >> 1, ck = s & 1;
    const int ky = tap / 3, kx = tap % 3;
    const int gy = h + ky - 1;
    const bool gyok = ((unsigned)gy < (unsigned)Hn);
    const int gyc = min(max(gy, 0), Hn - 1);

    bf16x8 af[2][2];
#pragma unroll
    for (int mt = 0; mt < 2; ++mt) {
      int wpos = mi * 32 + mt * 16 + lm;
      int gx = wpos + kx - 1;
      bool ok = gyok && ((unsigned)gx < (unsigned)Wn);
      int gxc = min(max(gx, 0), Wn - 1);
      const unsigned short* ap = xb + (((long)(b * HWn + gyc * Wn + gxc)) << 7)
                                    + ck * 64 + lh * 8;
#pragma unroll
      for (int ksub = 0; ksub < 2; ++ksub) {
        bf16x8 v = *(const bf16x8*)(ap + ksub * 32);
        af[mt][ksub] = ok ? v : (bf16x8)(short)0;
      }
    }

    const char* wbase = (const char*)&wlds[cur][0];
#pragma unroll
    for (int ksub = 0; ksub < 2; ++ksub) {
      int jj = ksub * 4 + lh;
#pragma unroll
      for (int nt = 0; nt < 7; ++nt) {
        int oc = ni * 112 + nt * 16 + lm;
        bf16x8 bfv = *(const bf16x8*)(wbase + oc * 128 + ((jj ^ (oc & 7)) << 4));
#pragma unroll
        for (int mt = 0; mt < 2; ++mt)
          acc[mt][nt] = __builtin_amdgcn_mfma_f32_16x16x32_bf16(
              af[mt][ksub], bfv, acc[mt][nt], 0, 0, 0);
      }
    }
    __syncthreads();
  }

#pragma unroll
  for (int nt = 0; nt < 7; ++nt) {
    int ch = ni * 112 + nt * 16 + lm;
    if (ch >= CMn) continue;
    float bias = bcm[ch];
#pragma unroll
    for (int mt = 0; mt < 2; ++mt) {
#pragma unroll
      for (int r = 0; r < 4; ++r) {
        int w = mi * 32 + mt * 16 + lh * 4 + r;
        float v = acc[mt][nt][r] + bias;
        if (ch >= 144) v = 1.0f / (1.0f + expf(-v));
        om[((long)((b * Hn + h) * CMn + ch) << 6) + w] = v;
      }
    }
  }
}

// ---------------- fused DCN v2: 8-wave, tap-parity dbuf, XOR-swizzled val ----------------
__global__ __launch_bounds__(512, 6) void k_dcn(const float* __restrict__ om,
                                                const unsigned short* __restrict__ fupb,
                                                const unsigned short* __restrict__ wdb,
                                                const float* __restrict__ bdc,
                                                const float* __restrict__ farm,
                                                void* __restrict__ out,
                                                const int* __restrict__ flagp) {
  __shared__ char valb[2][32 * 256];
  const int h = blockIdx.x, b = blockIdx.y, w0 = blockIdx.z * 32;
  const int t = threadIdx.x;
  const int lane = t & 63, wid = t >> 6;
  const int lm = lane & 15, lh = lane >> 4;
  const int gw = t & 31, g = (t >> 5) & 7, half = t >> 8;

  f32x4 acc[2];
  acc[0] = (f32x4){0.f, 0.f, 0.f, 0.f};
  acc[1] = (f32x4){0.f, 0.f, 0.f, 0.f};

  const float* omr = om + ((long)(b * Hn + h) * CMn << 6);
  const unsigned short* fb = fupb + ((long)b << 19) + g * 16 + half * 8;
  const int wcol = w0 + gw;

  union U4 { uint4 q; unsigned short s[8]; };

#pragma unroll
  for (int k = 0; k < Kn; ++k) {
    int ch = g * Kn + k;
    float oy = omr[(ch << 6) + wcol];
    float ox = omr[((72 + ch) << 6) + wcol];
    float mk = omr[((144 + ch) << 6) + wcol];
    float py = (float)(h + k / 3 - 1) + oy;
    float px = (float)(wcol + k % 3 - 1) + ox;
    float fy = floorf(py), fx = floorf(px);
    float ly = py - fy, lx = px - fx;
    int y0 = (int)fy, x0 = (int)fx, y1 = y0 + 1, x1 = x0 + 1;
    float vy0 = (y0 >= 0 && y0 < Hn) ? 1.f : 0.f;
    float vy1 = (y1 >= 0 && y1 < Hn) ? 1.f : 0.f;
    float vx0 = (x0 >= 0 && x0 < Wn) ? 1.f : 0.f;
    float vx1 = (x1 >= 0 && x1 < Wn) ? 1.f : 0.f;
    int cy0 = min(max(y0, 0), Hn - 1), cy1 = min(max(y1, 0), Hn - 1);
    int cx0 = min(max(x0, 0), Wn - 1), cx1 = min(max(x1, 0), Wn - 1);
    float wq0 = (1.f - ly) * (1.f - lx) * vy0 * vx0 * mk;
    float wq1 = (1.f - ly) * lx * vy0 * vx1 * mk;
    float wq2 = ly * (1.f - lx) * vy1 * vx0 * mk;
    float wq3 = ly * lx * vy1 * vx1 * mk;
    U4 c0v, c1v, c2v, c3v;
    c0v.q = *(const uint4*)(fb + ((long)(cy0 * Wn + cx0) << 7));
    c1v.q = *(const uint4*)(fb + ((long)(cy0 * Wn + cx1) << 7));
    c2v.q = *(const uint4*)(fb + ((long)(cy1 * Wn + cx0) << 7));
    c3v.q = *(const uint4*)(fb + ((long)(cy1 * Wn + cx1) << 7));
    float v[8];
#pragma unroll
    for (int j = 0; j < 8; ++j)
      v[j] = wq0 * b2f(c0v.s[j]) + wq1 * b2f(c1v.s[j]) +
             wq2 * b2f(c2v.s[j]) + wq3 * b2f(c3v.s[j]);
    uint4 pk;
    pk.x = pack2(v[0], v[1]); pk.y = pack2(v[2], v[3]);
    pk.z = pack2(v[4], v[5]); pk.w = pack2(v[6], v[7]);
    // XOR-swizzled write: chunk = g*2+half, chunk ^= (row&7)<<1
    int chunk = g * 2 + half;
    *(uint4*)(valb[k & 1] + gw * 256 + ((chunk ^ ((gw & 7) << 1)) << 4)) = pk;
    __syncthreads();

    const char* base = valb[k & 1];
    const unsigned short* wkb = wdb + (long)k * Cn * Cn + (long)(wid * 16 + lm) * Cn;
#pragma unroll
    for (int ks = 0; ks < 4; ++ks) {
      int rchunk = (ks * 4 + lh) ^ ((lm & 7) << 1);
      bf16x8 af0 = *(const bf16x8*)(base + lm * 256 + (rchunk << 4));
      bf16x8 af1 = *(const bf16x8*)(base + (16 + lm) * 256 + (rchunk << 4));
      bf16x8 bfv = *(const bf16x8*)(wkb + ks * 32 + lh * 8);
      acc[0] = __builtin_amdgcn_mfma_f32_16x16x32_bf16(af0, bfv, acc[0], 0, 0, 0);
      acc[1] = __builtin_amdgcn_mfma_f32_16x16x32_bf16(af1, bfv, acc[1], 0, 0, 0);
    }
  }

  bool isbf = (*flagp != 0);
  const int o = wid * 16 + lm;
  const float bias = bdc[o];
#pragma unroll
  for (int mt = 0; mt < 2; ++mt) {
#pragma unroll
    for (int r = 0; r < 4; ++r) {
      int w = w0 + mt * 16 + lh * 4 + r;
      long oi = (long)(b * Cn + o) * HWn + h * Wn + w;
      float v = acc[mt][r] + bias;
      v = fmaxf(v, 0.f) + farm[oi];
      if (isbf) ((__hip_bfloat16*)out)[oi] = __float2bfloat16(v);
      else      ((float*)out)[oi] = v;
    }
  }
}

// ---------------- launcher ----------------
extern "C" void kernel_launch(void* const* d_in, const int* in_sizes, int n_in,
                              void* d_out, int out_size, void* d_ws, size_t ws_size,
                              hipStream_t stream) {
  (void)in_sizes; (void)n_in; (void)out_size; (void)ws_size;
  const void* feat_l  = d_in[0];
  const void* feat_s  = d_in[1];
  const void* w_atten = d_in[2];
  const void* w_fsm   = d_in[3];
  const void* w_off   = d_in[4];
  const void* w_cm    = d_in[5];
  const void* b_cm    = d_in[6];
  const void* w_dcn   = d_in[7];
  const void* b_dcn   = d_in[8];
  float* ws = (float*)d_ws;
  int* flagw = (int*)d_ws;
  const int* flag = (const int*)d_ws;
  unsigned short* flb  = (unsigned short*)(ws + OFF_FLB);
  unsigned short* fupb = (unsigned short*)(ws + OFF_FUPB);
  unsigned short* oftb = (unsigned short*)(ws + OFF_OFT);
  unsigned short* wcb  = (unsigned short*)(ws + OFF_WCT);
  unsigned short* wdb  = (unsigned short*)(ws + OFF_WDT);
  unsigned short* w1tb = (unsigned short*)(ws + OFF_W1TB);
  unsigned short* wcat = (unsigned short*)(ws + OFF_WCAT);

  k_detect<<<1, 256, 0, stream>>>((const unsigned int*)feat_l, flagw);
  k_cvtl<<<dim3(64, 8), 256, 0, stream>>>(feat_l, flb, flag);
  k_upbf<<<dim3(64, 8), 256, 0, stream>>>(feat_s, fupb, flag);
  k_cvt<<<1, 256, 0, stream>>>(b_cm, ws + OFF_BCM, CMn, flag);
  k_cvt<<<1, 256, 0, stream>>>(b_dcn, ws + OFF_BDC, Cn, flag);
  k_wcmB<<<(18 * 224 * 64 + 255) / 256, 256, 0, stream>>>(w_cm, wcb, flag);
  k_wdcnB<<<(Kn * Cn * Cn + 255) / 256, 256, 0, stream>>>(w_dcn, wdb, flag);
  hipMemsetAsync(ws + OFF_GAP, 0, 1024 * sizeof(float), stream);
  k_gap2<<<dim3(8, 8), 256, 0, stream>>>(flb, ws + OFF_GAP);
  k_atten<<<4, 256, 0, stream>>>(ws + OFF_GAP, w_atten, ws + OFF_AT, flag);
  k_pmat<<<64, 256, 0, stream>>>(w_off, w_fsm, ws + OFF_P, flag);
  k_wprep<<<(Bn * 49152 + 255) / 256, 256, 0, stream>>>(w_fsm, w_off, ws + OFF_P,
                                                        ws + OFF_AT, w1tb, wcat, flag);
  k_farm<<<dim3(64, 8), 256, 0, stream>>>(flb, w1tb, ws + OFF_FARM);
  k_offf<<<dim3(64, 8), 256, 0, stream>>>(flb, fupb, wcat, oftb);
  k_convcm<<<dim3(64, 8), 256, 0, stream>>>(oftb, wcb, ws + OFF_BCM, ws + OFF_OM);
  k_dcn<<<dim3(64, 8, 2), 512, 0, stream>>>(ws + OFF_OM, fupb, wdb,
                                            ws + OFF_BDC, ws + OFF_FARM, d_out, flag);
}